// Round 20
// baseline (295.909 us; speedup 1.0000x reference)
//
#include <hip/hip_runtime.h>
#include <hip/hip_bf16.h>

#define B_  16
#define N_  512
#define K_  512
#define HF_ 512
#define NH_ 8

// ---- numpy f32 emulation helpers (explicit roundings; no contraction) ----
__device__ __forceinline__ float f_add(float a, float b){ return __fadd_rn(a,b); }
__device__ __forceinline__ float f_sub(float a, float b){ return __fsub_rn(a,b); }
__device__ __forceinline__ float f_mul(float a, float b){ return __fmul_rn(a,b); }
__device__ __forceinline__ float f_fma(float a, float b, float c){ return __fmaf_rn(a,b,c); }
__device__ __forceinline__ float f_div(float a, float b){ return __fdiv_rn(a,b); }
__device__ __forceinline__ float expf_cr(float x){ return (float)exp((double)x); }
__device__ __forceinline__ float lrelu_np(float x){ return x >= 0.f ? x : f_mul(0.1f, x); }

// XCD-aware chunked block swizzle (bijective when nwg%8==0 — true for all grids here).
__device__ __forceinline__ int swz8(int phys, int nwg){
  const int cpx = nwg >> 3;
  return (phys & 7)*cpx + (phys >> 3);
}

// ---- neighbor lists, built ONCE per chunk — VERBATIM round 18 (known-pass). ----
__global__ __launch_bounds__(256) void build_lists(const float* __restrict__ adjc,
                                                   unsigned short* __restrict__ lists,
                                                   int* __restrict__ cnts){
  const int w = (blockIdx.x*256 + threadIdx.x) >> 6;
  const int lane = threadIdx.x & 63;
  const int bc = w >> 9, gi = w & 511;
  const float* arow = adjc + ((size_t)(bc*N_)+gi)*N_;
  unsigned short* lp = lists + ((size_t)(bc*N_)+gi)*128;
  int cnt = 0;
  for (int cc=0; cc<8; ++cc){
    const int j = cc*64 + lane;
    const bool pred = (arow[j] != 0.f) || (gi == j);
    const unsigned long long mb = __ballot(pred);
    if (pred){
      const int pos = cnt + __popcll(mb & ((1ull<<lane)-1ull));
      if (pos < 128) lp[pos] = (unsigned short)j;
    }
    cnt += (int)__popcll(mb);
  }
  if (lane == 0) cnts[bc*N_+gi] = cnt;
}

// ---- sgemm emu, 128x128 tile, BK=16, 8m x 8c per thread, reg-buffered pipeline.
// Per-element FP: identical sequential-k 512-FMA chain; only tiling/staging change. ----
__global__ __launch_bounds__(256) void gemm_t(const float* __restrict__ A, const float* __restrict__ W,
                                              float* __restrict__ C){
  __shared__ float As2[16][132];  // [k][m], m=128
  __shared__ float Ws[16][132];   // [k][c], c=128
  const int t  = threadIdx.x;
  const int nb = gridDim.x*gridDim.y;
  const int id = swz8(blockIdx.y*gridDim.x + blockIdx.x, nb);
  const int c0 = (id & 3)*128, m0 = (id >> 2)*128;
  const int mg = t>>4, cg = t&15;          // 8m x 8c per thread
  const int arow = t>>1, akk = (t&1)*8;    // A stage: row, 8 k
  const int wr = t>>4, wcc = (t&15)*8;     // W stage: k row, 8 c
  float4 av0, av1, wv0, wv1;
  {
    const float* ap = A + (size_t)(m0+arow)*K_ + akk;
    av0 = *reinterpret_cast<const float4*>(ap);
    av1 = *reinterpret_cast<const float4*>(ap+4);
    const float* wp = W + (size_t)wr*HF_ + c0 + wcc;
    wv0 = *reinterpret_cast<const float4*>(wp);
    wv1 = *reinterpret_cast<const float4*>(wp+4);
  }
  float acc[8][8] = {};
  for (int kt=0; kt<K_; kt+=16){
    __syncthreads();   // previous compute done reading LDS
    As2[akk+0][arow]=av0.x; As2[akk+1][arow]=av0.y; As2[akk+2][arow]=av0.z; As2[akk+3][arow]=av0.w;
    As2[akk+4][arow]=av1.x; As2[akk+5][arow]=av1.y; As2[akk+6][arow]=av1.z; As2[akk+7][arow]=av1.w;
    *reinterpret_cast<float4*>(&Ws[wr][wcc])   = wv0;
    *reinterpret_cast<float4*>(&Ws[wr][wcc+4]) = wv1;
    __syncthreads();
    if (kt+16 < K_){   // prefetch next K-step; latency hides under compute below
      const float* ap = A + (size_t)(m0+arow)*K_ + kt + 16 + akk;
      av0 = *reinterpret_cast<const float4*>(ap);
      av1 = *reinterpret_cast<const float4*>(ap+4);
      const float* wp = W + (size_t)(kt+16+wr)*HF_ + c0 + wcc;
      wv0 = *reinterpret_cast<const float4*>(wp);
      wv1 = *reinterpret_cast<const float4*>(wp+4);
    }
    #pragma unroll
    for (int k=0;k<16;++k){
      const float4 a40 = *reinterpret_cast<const float4*>(&As2[k][mg*8]);
      const float4 a41 = *reinterpret_cast<const float4*>(&As2[k][mg*8+4]);
      const float4 w40 = *reinterpret_cast<const float4*>(&Ws[k][cg*8]);
      const float4 w41 = *reinterpret_cast<const float4*>(&Ws[k][cg*8+4]);
      const float am[8] = {a40.x,a40.y,a40.z,a40.w,a41.x,a41.y,a41.z,a41.w};
      const float wm[8] = {w40.x,w40.y,w40.z,w40.w,w41.x,w41.y,w41.z,w41.w};
      #pragma unroll
      for (int q=0;q<8;++q)
        #pragma unroll
        for (int p=0;p<8;++p)
          acc[q][p] = f_fma(am[q], wm[p], acc[q][p]);
    }
  }
  #pragma unroll
  for (int q=0;q<8;++q){
    float4 o0 = make_float4(acc[q][0],acc[q][1],acc[q][2],acc[q][3]);
    float4 o1 = make_float4(acc[q][4],acc[q][5],acc[q][6],acc[q][7]);
    float* cp = &C[(size_t)(m0+mg*8+q)*HF_ + c0 + cg*8];
    *reinterpret_cast<float4*>(cp)   = o0;
    *reinterpret_cast<float4*>(cp+4) = o1;
  }
}

// ---- el/er: unchanged ----
__global__ __launch_bounds__(256) void eler_emu(const float* __restrict__ g, const float* __restrict__ a,
                                                float* __restrict__ el, float* __restrict__ er){
  const int gid = blockIdx.x*256 + threadIdx.x;   // (row, h)
  const int row = gid >> 3, h = gid & 7;
  const float* gr = g + (size_t)row*HF_ + h*64;
  float pl = 0.f, pr = 0.f;
  for (int f=0; f<64; ++f){
    pl = f_add(pl, f_mul(gr[f], a[f]));
    pr = f_add(pr, f_mul(gr[f], a[64+f]));
  }
  el[(size_t)row*NH_+h] = pl;
  er[(size_t)row*NH_+h] = pr;
}

// ---- attention: VERBATIM round 18/19 (known-pass; scalar LDS only). ----
__global__ __launch_bounds__(256) void att_sp(const float* __restrict__ g, const float* __restrict__ el,
                                              const float* __restrict__ er, const float* __restrict__ adjc,
                                              const unsigned short* __restrict__ lists,
                                              const int* __restrict__ cnts,
                                              float* __restrict__ hout){
  const int bid = swz8(blockIdx.x, gridDim.x);
  const int it = bid & 31, h = (bid>>5)&7, bc = bid>>8;
  const int i0 = it*16;
  __shared__ float er_s[512];
  __shared__ float el_s[16];
  __shared__ unsigned short list_s[16][128];
  __shared__ float pval_s[16][128];
  __shared__ int   cnt_s[16];
  __shared__ float m_s[16], den_s[16];
  __shared__ float rs[16][33];
  __shared__ float dense_s[513];   // overflow-fallback only
  __shared__ float red[256];       // overflow-fallback only
  const int t = threadIdx.x;
  if (t < 16){ el_s[t] = el[((size_t)(bc*N_) + i0 + t)*NH_ + h]; cnt_s[t] = cnts[bc*N_+i0+t]; }
  er_s[t]     = er[((size_t)(bc*N_) + t)*NH_ + h];
  er_s[t+256] = er[((size_t)(bc*N_) + t + 256)*NH_ + h];
  {
    const int r = t>>4, off = (t&15)*8;
    const unsigned short* lp = lists + ((size_t)(bc*N_)+i0+r)*128 + off;
    #pragma unroll
    for (int q=0;q<8;++q) list_s[r][off+q] = lp[q];
  }
  __syncthreads();
  const int ir = t>>4, l = t&15;
  // e in list order + per-lane max
  {
    const int cnt = cnt_s[ir];
    const float eli = el_s[ir];
    float mx = -INFINITY;
    if (cnt <= 128){
      for (int kk=l; kk<cnt; kk+=16){
        const float e = lrelu_np(f_add(eli, er_s[list_s[ir][kk]]));
        pval_s[ir][kk] = e;
        mx = fmaxf(mx, e);
      }
    }
    rs[ir][l] = mx;
  }
  __syncthreads();
  if (t < 16){
    float m = rs[t][0];
    #pragma unroll
    for (int u=1;u<16;++u) m = fmaxf(m, rs[t][u]);
    m_s[t] = m;
  }
  __syncthreads();
  // exp over list
  {
    const int cnt = cnt_s[ir];
    const float mi = m_s[ir];
    if (cnt <= 128)
      for (int kk=l; kk<cnt; kk+=16)
        pval_s[ir][kk] = expf_cr(f_sub(pval_s[ir][kk], mi));
  }
  __syncthreads();
  // den: numpy pairwise via slot-sums (thread owns slots l and l+16 of row ir) — SCALAR
  {
    const int cnt = cnt_s[ir];
    if (cnt <= 128){
      #pragma unroll
      for (int ss=0; ss<2; ++ss){
        const int s = l + ss*16;
        float r = 0.f;
        for (int kk=0; kk<cnt; ++kk){
          const int j = list_s[ir][kk];
          const int slot = ((j>>7)<<3) | (j&7);
          if (slot == s) r = f_add(r, pval_s[ir][kk]);
        }
        rs[ir][s] = r;
      }
    }
  }
  __syncthreads();
  if (t < 16 && cnt_s[t] <= 128){
    float pw[4];
    #pragma unroll
    for (int gq=0;gq<4;++gq){
      const float* rr = &rs[t][gq*8];
      pw[gq] = f_add(f_add(f_add(rr[0],rr[1]),f_add(rr[2],rr[3])),
                     f_add(f_add(rr[4],rr[5]),f_add(rr[6],rr[7])));
    }
    den_s[t] = f_add(f_add(pw[0],pw[1]), f_add(pw[2],pw[3]));
  }
  __syncthreads();
  // div over list
  {
    const int cnt = cnt_s[ir];
    const float di = den_s[ir];
    if (cnt <= 128)
      for (int kk=l; kk<cnt; kk+=16)
        pval_s[ir][kk] = f_div(pval_s[ir][kk], di);
  }
  __syncthreads();
  // aggregation: sparse j-ascending chain per (row, f) — SCALAR
  {
    const int f = t & 63, iw = t >> 6;
    const float* gcol = g + (size_t)(bc*N_)*HF_ + h*64 + f;
    const size_t ob = (size_t)(bc*N_) + i0;
    #pragma unroll
    for (int q=0;q<4;++q){
      const int i = iw + q*4;
      const int cnt = cnt_s[i];
      if (cnt > 128) continue;
      float a = 0.f;
      for (int kk=0; kk<cnt; ++kk){
        const int j = list_s[i][kk];
        a = f_add(a, f_mul(pval_s[i][kk], gcol[(size_t)j*HF_]));
      }
      hout[(ob+i)*HF_ + h*64 + f] = lrelu_np(a);
    }
  }
  // dense fallback for overflow rows (cnt>128; kept for unconditional correctness)
  for (int i=0;i<16;++i){
    if (cnt_s[i] <= 128) continue;
    __syncthreads();
    const int gi = i0 + i;
    const float eli = el_s[i];
    for (int s=0;s<2;++s){
      const int j = t + s*256;
      const float av = adjc[((size_t)(bc*N_)+gi)*N_ + j];
      const bool mask = (av != 0.f) || (gi == j);
      dense_s[j] = mask ? lrelu_np(f_add(eli, er_s[j])) : -1000.0f;
    }
    __syncthreads();
    red[t] = fmaxf(dense_s[t], dense_s[t+256]);
    __syncthreads();
    for (int s2=128; s2>=1; s2>>=1){ if (t<s2) red[t]=fmaxf(red[t],red[t+s2]); __syncthreads(); }
    const float mi = red[0];
    __syncthreads();
    for (int s=0;s<2;++s){
      const int j = t + s*256;
      const float v = dense_s[j];
      dense_s[j] = (v == -1000.0f) ? 0.0f : expf_cr(f_sub(v, mi));
    }
    __syncthreads();
    if (t < 32){
      const int gq = t>>3, ll = t&7;
      float r = dense_s[gq*128 + ll];
      for (int m2=1;m2<16;++m2) r = f_add(r, dense_s[gq*128 + m2*8 + ll]);
      rs[0][t] = r;
    }
    __syncthreads();
    if (t == 0){
      float pw[4];
      for (int gq=0;gq<4;++gq){
        const float* rr = &rs[0][gq*8];
        pw[gq] = f_add(f_add(f_add(rr[0],rr[1]),f_add(rr[2],rr[3])),
                       f_add(f_add(rr[4],rr[5]),f_add(rr[6],rr[7])));
      }
      den_s[0] = f_add(f_add(pw[0],pw[1]), f_add(pw[2],pw[3]));
    }
    __syncthreads();
    {
      const float di = den_s[0];
      for (int s=0;s<2;++s){ const int j=t+s*256; dense_s[j] = f_div(dense_s[j], di); }
    }
    __syncthreads();
    if (t < 64){
      const float* gcol = g + (size_t)(bc*N_)*HF_ + h*64 + t;
      float a = 0.f;
      for (int j=0;j<512;++j) a = f_add(a, f_mul(dense_s[j], gcol[(size_t)j*HF_]));
      hout[((size_t)(bc*N_)+gi)*HF_ + h*64 + t] = lrelu_np(a);
    }
  }
}

// ---- scores: unchanged ----
__global__ __launch_bounds__(256) void scores_emu(const float* __restrict__ h2, const float* __restrict__ Wp,
                                                  const float* __restrict__ bp, float* __restrict__ sc){
  const int r = blockIdx.x*256 + threadIdx.x;   // (bc, n)
  const float* hr = h2 + (size_t)r*HF_;
  float q0=0,q1=0,q2=0,q3=0,q4=0,q5=0,q6=0,q7=0;
  for (int k=0;k<512;k+=8){
    q0=f_fma(hr[k+0],Wp[k+0],q0); q1=f_fma(hr[k+1],Wp[k+1],q1);
    q2=f_fma(hr[k+2],Wp[k+2],q2); q3=f_fma(hr[k+3],Wp[k+3],q3);
    q4=f_fma(hr[k+4],Wp[k+4],q4); q5=f_fma(hr[k+5],Wp[k+5],q5);
    q6=f_fma(hr[k+6],Wp[k+6],q6); q7=f_fma(hr[k+7],Wp[k+7],q7);
  }
  const float d = f_add(f_add(f_add(q0,q4),f_add(q1,q5)), f_add(f_add(q2,q6),f_add(q3,q7)));
  sc[r] = f_add(d, bp[0]);
}

// ---- stable top-256 rank counting (unchanged) ----
__global__ __launch_bounds__(512) void topk_f(const float* __restrict__ sc, int* __restrict__ idx){
  __shared__ float sl[512];
  const int b = blockIdx.x, t = threadIdx.x;
  if (t < 256) idx[b*256+t] = t;
  sl[t] = sc[(size_t)b*N_+t];
  __syncthreads();
  const float mine = sl[t];
  int cnt = 0;
  for (int j=0;j<N_;++j){
    const float v = sl[j];
    cnt += (v > mine) || (v == mine && j < t);
  }
  if (cnt < 256) idx[b*256+cnt] = t;
}

__global__ __launch_bounds__(128) void gather_f(const float* __restrict__ h2, const int* __restrict__ idx,
                                                float* __restrict__ outc){
  const int r = blockIdx.x;
  const int bc = r>>8, kk = r&255;
  const int n = idx[bc*256+kk] & (N_-1);
  const int t = threadIdx.x;
  const float4 v = *reinterpret_cast<const float4*>(&h2[(size_t)(bc*N_+n)*HF_ + t*4]);
  *reinterpret_cast<float4*>(&outc[(size_t)(bc*256+kk)*HF_ + t*4]) = v;
}

extern "C" void kernel_launch(void* const* d_in, const int* in_sizes, int n_in,
                              void* d_out, int out_size, void* d_ws, size_t ws_size,
                              hipStream_t stream){
  const float* x   = (const float*)d_in[0];
  const float* adj = (const float*)d_in[1];
  const float* W1  = (const float*)d_in[2];
  const float* a1  = (const float*)d_in[3];
  const float* W2  = (const float*)d_in[4];
  const float* a2  = (const float*)d_in[5];
  const float* Wp  = (const float*)d_in[6];
  const float* bp  = (const float*)d_in[7];

  // per-batch: g/h1/h2 1MiB each + el/er 16KiB + sc 2KiB + idx 1KiB + lists 128KiB + cnts 2KiB
  const size_t per = 3314688;
  int C = B_;
  while (C > 1 && per*(size_t)C > ws_size) C >>= 1;

  char* w    = (char*)d_ws;
  float* g   = (float*)w;
  float* h1  = (float*)(w + (size_t)C*1048576);
  float* h2  = (float*)(w + (size_t)2*C*1048576);
  float* el  = (float*)(w + (size_t)3*C*1048576);
  float* er  = el + (size_t)C*4096;
  float* sc  = er + (size_t)C*4096;
  int*  idx  = (int*)(sc + (size_t)C*512);
  unsigned short* lists = (unsigned short*)((char*)idx + (size_t)C*1024);
  int*  cnts = (int*)((char*)lists + (size_t)C*131072);

  for (int b0 = 0; b0 < B_; b0 += C){
    const float* xc   = x   + (size_t)b0*N_*K_;
    const float* adjc = adj + (size_t)b0*N_*N_;
    float* outc = (float*)d_out + (size_t)b0*256*HF_;
    const int M = C*N_;
    dim3 gg(HF_/128, M/128);
    build_lists<<<C*128, 256, 0, stream>>>(adjc, lists, cnts);
    // layer 1
    gemm_t<<<gg, 256, 0, stream>>>(xc, W1, g);
    eler_emu<<<(M*NH_)/256, 256, 0, stream>>>(g, a1, el, er);
    att_sp<<<C*NH_*32, 256, 0, stream>>>(g, el, er, adjc, lists, cnts, h1);
    // layer 2
    gemm_t<<<gg, 256, 0, stream>>>(h1, W2, g);
    eler_emu<<<(M*NH_)/256, 256, 0, stream>>>(g, a2, el, er);
    att_sp<<<C*NH_*32, 256, 0, stream>>>(g, el, er, adjc, lists, cnts, h2);
    // pool
    scores_emu<<<M/256, 256, 0, stream>>>(h2, Wp, bp, sc);
    topk_f<<<C, 512, 0, stream>>>(sc, idx);
    gather_f<<<C*256, 128, 0, stream>>>(h2, idx, outc);
  }
}

// Round 21
// 275.872 us; speedup vs baseline: 1.0726x; 1.0726x over previous
//
#include <hip/hip_runtime.h>
#include <hip/hip_bf16.h>

#define B_  16
#define N_  512
#define K_  512
#define HF_ 512
#define NH_ 8

// ---- numpy f32 emulation helpers (explicit roundings; no contraction) ----
__device__ __forceinline__ float f_add(float a, float b){ return __fadd_rn(a,b); }
__device__ __forceinline__ float f_sub(float a, float b){ return __fsub_rn(a,b); }
__device__ __forceinline__ float f_mul(float a, float b){ return __fmul_rn(a,b); }
__device__ __forceinline__ float f_fma(float a, float b, float c){ return __fmaf_rn(a,b,c); }
__device__ __forceinline__ float f_div(float a, float b){ return __fdiv_rn(a,b); }
__device__ __forceinline__ float expf_cr(float x){ return (float)exp((double)x); }
__device__ __forceinline__ float lrelu_np(float x){ return x >= 0.f ? x : f_mul(0.1f, x); }

// XCD-aware chunked block swizzle (bijective when nwg%8==0 — true for all grids here).
__device__ __forceinline__ int swz8(int phys, int nwg){
  const int cpx = nwg >> 3;
  return (phys & 7)*cpx + (phys >> 3);
}

// ---- neighbor lists + slot-major index, built ONCE per chunk.
// List order identical to r18 (ascending-j ballot compaction). NEW: per row, slotkk = list
// indices reordered slot-major (slot(j) = (j>>7)*8 + (j&7)), soff[33] = slot start offsets.
// Integer-only addition; list/cnt semantics unchanged. ----
__global__ __launch_bounds__(256) void build_lists(const float* __restrict__ adjc,
                                                   unsigned short* __restrict__ lists,
                                                   int* __restrict__ cnts,
                                                   unsigned short* __restrict__ slotkk,
                                                   unsigned short* __restrict__ soff){
  __shared__ unsigned short ll_s[4][128];
  __shared__ int scn_s[4][32];
  const int wv = threadIdx.x >> 6;
  const int w = (blockIdx.x*256 + threadIdx.x) >> 6;
  const int lane = threadIdx.x & 63;
  const int bc = w >> 9, gi = w & 511;
  const float* arow = adjc + ((size_t)(bc*N_)+gi)*N_;
  const size_t rb = (size_t)(bc*N_)+gi;
  unsigned short* lp = lists + rb*128;
  ll_s[wv][lane] = 0; ll_s[wv][lane+64] = 0;
  int cnt = 0;
  for (int cc=0; cc<8; ++cc){
    const int j = cc*64 + lane;
    const bool pred = (arow[j] != 0.f) || (gi == j);
    const unsigned long long mb = __ballot(pred);
    if (pred){
      const int pos = cnt + __popcll(mb & ((1ull<<lane)-1ull));
      if (pos < 128) ll_s[wv][pos] = (unsigned short)j;
    }
    cnt += (int)__popcll(mb);
  }
  if (lane == 0) cnts[bc*N_+gi] = cnt;
  __syncthreads();
  // write list to global (identical content/order as r18's direct writes)
  lp[lane]    = ll_s[wv][lane];
  lp[lane+64] = ll_s[wv][lane+64];
  // per-slot counts (lane < 32 owns slot = lane)
  if (cnt <= 128 && lane < 32){
    int myc = 0;
    for (int kk=0; kk<cnt; ++kk){
      const int j = ll_s[wv][kk];
      const int sl = ((j>>7)<<3) | (j&7);
      myc += (sl == lane);
    }
    scn_s[wv][lane] = myc;
  }
  __syncthreads();
  if (cnt <= 128 && lane < 32){
    const int s = lane;
    int off = 0;
    for (int u=0; u<s; ++u) off += scn_s[wv][u];
    soff[rb*33 + s] = (unsigned short)off;
    if (s == 0) soff[rb*33 + 32] = (unsigned short)cnt;
    int pos = off;
    unsigned short* sk = slotkk + rb*128;
    for (int kk=0; kk<cnt; ++kk){
      const int j = ll_s[wv][kk];
      const int sl = ((j>>7)<<3) | (j&7);
      if (sl == s){ sk[pos] = (unsigned short)kk; ++pos; }
    }
  }
}

// ---- sgemm emu, 128x64 tile, BK=16, reg-buffered pipeline — VERBATIM round 19 (67.4 us). ----
__global__ __launch_bounds__(256) void gemm_t(const float* __restrict__ A, const float* __restrict__ W,
                                              float* __restrict__ C){
  __shared__ float As2[16][132];  // [k][m], m=128
  __shared__ float Ws[16][68];    // [k][c]
  const int t  = threadIdx.x;
  const int nb = gridDim.x*gridDim.y;
  const int id = swz8(blockIdx.y*gridDim.x + blockIdx.x, nb);
  const int c0 = (id & 7)*64, m0 = (id >> 3)*128;
  const int mg = t>>4, cg = t&15;   // 8m x 4c per thread
  const int arow = t>>1, akk = (t&1)*8;   // A stage: row, 8 k
  const int wr = t>>4, wcc = (t&15)*4;    // W stage: k row, 4 c
  float4 av0, av1, wv;
  {
    const float* ap = A + (size_t)(m0+arow)*K_ + akk;
    av0 = *reinterpret_cast<const float4*>(ap);
    av1 = *reinterpret_cast<const float4*>(ap+4);
    wv  = *reinterpret_cast<const float4*>(W + (size_t)wr*HF_ + c0 + wcc);
  }
  float acc[8][4] = {};
  for (int kt=0; kt<K_; kt+=16){
    __syncthreads();   // previous compute done reading LDS
    As2[akk+0][arow]=av0.x; As2[akk+1][arow]=av0.y; As2[akk+2][arow]=av0.z; As2[akk+3][arow]=av0.w;
    As2[akk+4][arow]=av1.x; As2[akk+5][arow]=av1.y; As2[akk+6][arow]=av1.z; As2[akk+7][arow]=av1.w;
    *reinterpret_cast<float4*>(&Ws[wr][wcc]) = wv;
    __syncthreads();
    if (kt+16 < K_){   // prefetch next K-step; latency hides under compute below
      const float* ap = A + (size_t)(m0+arow)*K_ + kt + 16 + akk;
      av0 = *reinterpret_cast<const float4*>(ap);
      av1 = *reinterpret_cast<const float4*>(ap+4);
      wv  = *reinterpret_cast<const float4*>(W + (size_t)(kt+16+wr)*HF_ + c0 + wcc);
    }
    #pragma unroll
    for (int k=0;k<16;++k){
      const float4 a40 = *reinterpret_cast<const float4*>(&As2[k][mg*8]);
      const float4 a41 = *reinterpret_cast<const float4*>(&As2[k][mg*8+4]);
      const float4 w4  = *reinterpret_cast<const float4*>(&Ws[k][cg*4]);
      const float am[8] = {a40.x,a40.y,a40.z,a40.w,a41.x,a41.y,a41.z,a41.w};
      #pragma unroll
      for (int q=0;q<8;++q){
        acc[q][0]=f_fma(am[q],w4.x,acc[q][0]); acc[q][1]=f_fma(am[q],w4.y,acc[q][1]);
        acc[q][2]=f_fma(am[q],w4.z,acc[q][2]); acc[q][3]=f_fma(am[q],w4.w,acc[q][3]);
      }
    }
  }
  #pragma unroll
  for (int q=0;q<8;++q){
    float4 o = make_float4(acc[q][0],acc[q][1],acc[q][2],acc[q][3]);
    *reinterpret_cast<float4*>(&C[(size_t)(m0+mg*8+q)*HF_ + c0 + cg*4]) = o;
  }
}

// ---- el/er: unchanged ----
__global__ __launch_bounds__(256) void eler_emu(const float* __restrict__ g, const float* __restrict__ a,
                                                float* __restrict__ el, float* __restrict__ er){
  const int gid = blockIdx.x*256 + threadIdx.x;   // (row, h)
  const int row = gid >> 3, h = gid & 7;
  const float* gr = g + (size_t)row*HF_ + h*64;
  float pl = 0.f, pr = 0.f;
  for (int f=0; f<64; ++f){
    pl = f_add(pl, f_mul(gr[f], a[f]));
    pr = f_add(pr, f_mul(gr[f], a[64+f]));
  }
  el[(size_t)row*NH_+h] = pl;
  er[(size_t)row*NH_+h] = pr;
}

// ---- attention: r18 VERBATIM except den uses the precomputed slot-major index.
// FP stream identical: slot s's entries are ascending-kk (= ascending-j), same f_add chain. ----
__global__ __launch_bounds__(256) void att_sp(const float* __restrict__ g, const float* __restrict__ el,
                                              const float* __restrict__ er, const float* __restrict__ adjc,
                                              const unsigned short* __restrict__ lists,
                                              const int* __restrict__ cnts,
                                              const unsigned short* __restrict__ slotkk,
                                              const unsigned short* __restrict__ soff,
                                              float* __restrict__ hout){
  const int bid = swz8(blockIdx.x, gridDim.x);
  const int it = bid & 31, h = (bid>>5)&7, bc = bid>>8;
  const int i0 = it*16;
  __shared__ float er_s[512];
  __shared__ float el_s[16];
  __shared__ unsigned short list_s[16][128];
  __shared__ float pval_s[16][128];
  __shared__ int   cnt_s[16];
  __shared__ float m_s[16], den_s[16];
  __shared__ float rs[16][33];
  __shared__ float dense_s[513];   // overflow-fallback only
  __shared__ float red[256];       // overflow-fallback only
  const int t = threadIdx.x;
  if (t < 16){ el_s[t] = el[((size_t)(bc*N_) + i0 + t)*NH_ + h]; cnt_s[t] = cnts[bc*N_+i0+t]; }
  er_s[t]     = er[((size_t)(bc*N_) + t)*NH_ + h];
  er_s[t+256] = er[((size_t)(bc*N_) + t + 256)*NH_ + h];
  {
    const int r = t>>4, off = (t&15)*8;
    const unsigned short* lp = lists + ((size_t)(bc*N_)+i0+r)*128 + off;
    #pragma unroll
    for (int q=0;q<8;++q) list_s[r][off+q] = lp[q];
  }
  __syncthreads();
  const int ir = t>>4, l = t&15;
  // e in list order + per-lane max
  {
    const int cnt = cnt_s[ir];
    const float eli = el_s[ir];
    float mx = -INFINITY;
    if (cnt <= 128){
      for (int kk=l; kk<cnt; kk+=16){
        const float e = lrelu_np(f_add(eli, er_s[list_s[ir][kk]]));
        pval_s[ir][kk] = e;
        mx = fmaxf(mx, e);
      }
    }
    rs[ir][l] = mx;
  }
  __syncthreads();
  if (t < 16){
    float m = rs[t][0];
    #pragma unroll
    for (int u=1;u<16;++u) m = fmaxf(m, rs[t][u]);
    m_s[t] = m;
  }
  __syncthreads();
  // exp over list
  {
    const int cnt = cnt_s[ir];
    const float mi = m_s[ir];
    if (cnt <= 128)
      for (int kk=l; kk<cnt; kk+=16)
        pval_s[ir][kk] = expf_cr(f_sub(pval_s[ir][kk], mi));
  }
  __syncthreads();
  // den: numpy pairwise via slot-sums, DIRECT via slot-major index (lane owns slots l, l+16)
  {
    const int cnt = cnt_s[ir];
    if (cnt <= 128){
      const size_t rb = (size_t)(bc*N_) + i0 + ir;
      const unsigned short* sk = slotkk + rb*128;
      const unsigned short* so = soff + rb*33;
      #pragma unroll
      for (int ss=0; ss<2; ++ss){
        const int s = l + ss*16;
        const int o0 = so[s], o1 = so[s+1];
        float r = 0.f;
        for (int o=o0; o<o1; ++o)
          r = f_add(r, pval_s[ir][sk[o]]);
        rs[ir][s] = r;
      }
    }
  }
  __syncthreads();
  if (t < 16 && cnt_s[t] <= 128){
    float pw[4];
    #pragma unroll
    for (int gq=0;gq<4;++gq){
      const float* rr = &rs[t][gq*8];
      pw[gq] = f_add(f_add(f_add(rr[0],rr[1]),f_add(rr[2],rr[3])),
                     f_add(f_add(rr[4],rr[5]),f_add(rr[6],rr[7])));
    }
    den_s[t] = f_add(f_add(pw[0],pw[1]), f_add(pw[2],pw[3]));
  }
  __syncthreads();
  // div over list
  {
    const int cnt = cnt_s[ir];
    const float di = den_s[ir];
    if (cnt <= 128)
      for (int kk=l; kk<cnt; kk+=16)
        pval_s[ir][kk] = f_div(pval_s[ir][kk], di);
  }
  __syncthreads();
  // aggregation: sparse j-ascending chain per (row, f) — SCALAR
  {
    const int f = t & 63, iw = t >> 6;
    const float* gcol = g + (size_t)(bc*N_)*HF_ + h*64 + f;
    const size_t ob = (size_t)(bc*N_) + i0;
    #pragma unroll
    for (int q=0;q<4;++q){
      const int i = iw + q*4;
      const int cnt = cnt_s[i];
      if (cnt > 128) continue;
      float a = 0.f;
      for (int kk=0; kk<cnt; ++kk){
        const int j = list_s[i][kk];
        a = f_add(a, f_mul(pval_s[i][kk], gcol[(size_t)j*HF_]));
      }
      hout[(ob+i)*HF_ + h*64 + f] = lrelu_np(a);
    }
  }
  // dense fallback for overflow rows (cnt>128; kept for unconditional correctness)
  for (int i=0;i<16;++i){
    if (cnt_s[i] <= 128) continue;
    __syncthreads();
    const int gi = i0 + i;
    const float eli = el_s[i];
    for (int s=0;s<2;++s){
      const int j = t + s*256;
      const float av = adjc[((size_t)(bc*N_)+gi)*N_ + j];
      const bool mask = (av != 0.f) || (gi == j);
      dense_s[j] = mask ? lrelu_np(f_add(eli, er_s[j])) : -1000.0f;
    }
    __syncthreads();
    red[t] = fmaxf(dense_s[t], dense_s[t+256]);
    __syncthreads();
    for (int s2=128; s2>=1; s2>>=1){ if (t<s2) red[t]=fmaxf(red[t],red[t+s2]); __syncthreads(); }
    const float mi = red[0];
    __syncthreads();
    for (int s=0;s<2;++s){
      const int j = t + s*256;
      const float v = dense_s[j];
      dense_s[j] = (v == -1000.0f) ? 0.0f : expf_cr(f_sub(v, mi));
    }
    __syncthreads();
    if (t < 32){
      const int gq = t>>3, ll = t&7;
      float r = dense_s[gq*128 + ll];
      for (int m2=1;m2<16;++m2) r = f_add(r, dense_s[gq*128 + m2*8 + ll]);
      rs[0][t] = r;
    }
    __syncthreads();
    if (t == 0){
      float pw[4];
      for (int gq=0;gq<4;++gq){
        const float* rr = &rs[0][gq*8];
        pw[gq] = f_add(f_add(f_add(rr[0],rr[1]),f_add(rr[2],rr[3])),
                       f_add(f_add(rr[4],rr[5]),f_add(rr[6],rr[7])));
      }
      den_s[0] = f_add(f_add(pw[0],pw[1]), f_add(pw[2],pw[3]));
    }
    __syncthreads();
    {
      const float di = den_s[0];
      for (int s=0;s<2;++s){ const int j=t+s*256; dense_s[j] = f_div(dense_s[j], di); }
    }
    __syncthreads();
    if (t < 64){
      const float* gcol = g + (size_t)(bc*N_)*HF_ + h*64 + t;
      float a = 0.f;
      for (int j=0;j<512;++j) a = f_add(a, f_mul(dense_s[j], gcol[(size_t)j*HF_]));
      hout[((size_t)(bc*N_)+gi)*HF_ + h*64 + t] = lrelu_np(a);
    }
  }
}

// ---- scores: unchanged ----
__global__ __launch_bounds__(256) void scores_emu(const float* __restrict__ h2, const float* __restrict__ Wp,
                                                  const float* __restrict__ bp, float* __restrict__ sc){
  const int r = blockIdx.x*256 + threadIdx.x;   // (bc, n)
  const float* hr = h2 + (size_t)r*HF_;
  float q0=0,q1=0,q2=0,q3=0,q4=0,q5=0,q6=0,q7=0;
  for (int k=0;k<512;k+=8){
    q0=f_fma(hr[k+0],Wp[k+0],q0); q1=f_fma(hr[k+1],Wp[k+1],q1);
    q2=f_fma(hr[k+2],Wp[k+2],q2); q3=f_fma(hr[k+3],Wp[k+3],q3);
    q4=f_fma(hr[k+4],Wp[k+4],q4); q5=f_fma(hr[k+5],Wp[k+5],q5);
    q6=f_fma(hr[k+6],Wp[k+6],q6); q7=f_fma(hr[k+7],Wp[k+7],q7);
  }
  const float d = f_add(f_add(f_add(q0,q4),f_add(q1,q5)), f_add(f_add(q2,q6),f_add(q3,q7)));
  sc[r] = f_add(d, bp[0]);
}

// ---- stable top-256 rank counting (unchanged) ----
__global__ __launch_bounds__(512) void topk_f(const float* __restrict__ sc, int* __restrict__ idx){
  __shared__ float sl[512];
  const int b = blockIdx.x, t = threadIdx.x;
  if (t < 256) idx[b*256+t] = t;
  sl[t] = sc[(size_t)b*N_+t];
  __syncthreads();
  const float mine = sl[t];
  int cnt = 0;
  for (int j=0;j<N_;++j){
    const float v = sl[j];
    cnt += (v > mine) || (v == mine && j < t);
  }
  if (cnt < 256) idx[b*256+cnt] = t;
}

__global__ __launch_bounds__(128) void gather_f(const float* __restrict__ h2, const int* __restrict__ idx,
                                                float* __restrict__ outc){
  const int r = blockIdx.x;
  const int bc = r>>8, kk = r&255;
  const int n = idx[bc*256+kk] & (N_-1);
  const int t = threadIdx.x;
  const float4 v = *reinterpret_cast<const float4*>(&h2[(size_t)(bc*N_+n)*HF_ + t*4]);
  *reinterpret_cast<float4*>(&outc[(size_t)(bc*256+kk)*HF_ + t*4]) = v;
}

extern "C" void kernel_launch(void* const* d_in, const int* in_sizes, int n_in,
                              void* d_out, int out_size, void* d_ws, size_t ws_size,
                              hipStream_t stream){
  const float* x   = (const float*)d_in[0];
  const float* adj = (const float*)d_in[1];
  const float* W1  = (const float*)d_in[2];
  const float* a1  = (const float*)d_in[3];
  const float* W2  = (const float*)d_in[4];
  const float* a2  = (const float*)d_in[5];
  const float* Wp  = (const float*)d_in[6];
  const float* bp  = (const float*)d_in[7];

  // per-batch: g/h1/h2 1MiB + el/er 16KiB + sc 2KiB + idx 1KiB + lists 128KiB + cnts 2KiB
  //            + slotkk 128KiB + soff 33.75KiB(512*66B)  => 3,480,320 (rounded up)
  const size_t per = 3480320;
  int C = B_;
  while (C > 1 && per*(size_t)C > ws_size) C >>= 1;

  char* w    = (char*)d_ws;
  float* g   = (float*)w;
  float* h1  = (float*)(w + (size_t)C*1048576);
  float* h2  = (float*)(w + (size_t)2*C*1048576);
  float* el  = (float*)(w + (size_t)3*C*1048576);
  float* er  = el + (size_t)C*4096;
  float* sc  = er + (size_t)C*4096;
  int*  idx  = (int*)(sc + (size_t)C*512);
  unsigned short* lists  = (unsigned short*)((char*)idx + (size_t)C*1024);
  int*  cnts             = (int*)((char*)lists + (size_t)C*131072);
  unsigned short* slotkk = (unsigned short*)((char*)cnts + (size_t)C*2048);
  unsigned short* soff   = (unsigned short*)((char*)slotkk + (size_t)C*131072);

  for (int b0 = 0; b0 < B_; b0 += C){
    const float* xc   = x   + (size_t)b0*N_*K_;
    const float* adjc = adj + (size_t)b0*N_*N_;
    float* outc = (float*)d_out + (size_t)b0*256*HF_;
    const int M = C*N_;
    dim3 gg(HF_/64, M/128);
    build_lists<<<C*128, 256, 0, stream>>>(adjc, lists, cnts, slotkk, soff);
    // layer 1
    gemm_t<<<gg, 256, 0, stream>>>(xc, W1, g);
    eler_emu<<<(M*NH_)/256, 256, 0, stream>>>(g, a1, el, er);
    att_sp<<<C*NH_*32, 256, 0, stream>>>(g, el, er, adjc, lists, cnts, slotkk, soff, h1);
    // layer 2
    gemm_t<<<gg, 256, 0, stream>>>(h1, W2, g);
    eler_emu<<<(M*NH_)/256, 256, 0, stream>>>(g, a2, el, er);
    att_sp<<<C*NH_*32, 256, 0, stream>>>(g, el, er, adjc, lists, cnts, slotkk, soff, h2);
    // pool
    scores_emu<<<M/256, 256, 0, stream>>>(h2, Wp, bp, sc);
    topk_f<<<C, 512, 0, stream>>>(sc, idx);
    gather_f<<<C*256, 128, 0, stream>>>(h2, idx, outc);
  }
}

// Round 22
// 273.123 us; speedup vs baseline: 1.0834x; 1.0101x over previous
//
#include <hip/hip_runtime.h>
#include <hip/hip_bf16.h>

#define B_  16
#define N_  512
#define K_  512
#define HF_ 512
#define NH_ 8

// ---- numpy f32 emulation helpers (explicit roundings; no contraction) ----
__device__ __forceinline__ float f_add(float a, float b){ return __fadd_rn(a,b); }
__device__ __forceinline__ float f_sub(float a, float b){ return __fsub_rn(a,b); }
__device__ __forceinline__ float f_mul(float a, float b){ return __fmul_rn(a,b); }
__device__ __forceinline__ float f_fma(float a, float b, float c){ return __fmaf_rn(a,b,c); }
__device__ __forceinline__ float f_div(float a, float b){ return __fdiv_rn(a,b); }
__device__ __forceinline__ float expf_cr(float x){ return (float)exp((double)x); }
__device__ __forceinline__ float lrelu_np(float x){ return x >= 0.f ? x : f_mul(0.1f, x); }

// XCD-aware chunked block swizzle (bijective when nwg%8==0 — true for all grids here).
__device__ __forceinline__ int swz8(int phys, int nwg){
  const int cpx = nwg >> 3;
  return (phys & 7)*cpx + (phys >> 3);
}

// ---- neighbor lists + slot-major index — VERBATIM round 21 (known-pass). ----
__global__ __launch_bounds__(256) void build_lists(const float* __restrict__ adjc,
                                                   unsigned short* __restrict__ lists,
                                                   int* __restrict__ cnts,
                                                   unsigned short* __restrict__ slotkk,
                                                   unsigned short* __restrict__ soff){
  __shared__ unsigned short ll_s[4][128];
  __shared__ int scn_s[4][32];
  const int wv = threadIdx.x >> 6;
  const int w = (blockIdx.x*256 + threadIdx.x) >> 6;
  const int lane = threadIdx.x & 63;
  const int bc = w >> 9, gi = w & 511;
  const float* arow = adjc + ((size_t)(bc*N_)+gi)*N_;
  const size_t rb = (size_t)(bc*N_)+gi;
  unsigned short* lp = lists + rb*128;
  ll_s[wv][lane] = 0; ll_s[wv][lane+64] = 0;
  int cnt = 0;
  for (int cc=0; cc<8; ++cc){
    const int j = cc*64 + lane;
    const bool pred = (arow[j] != 0.f) || (gi == j);
    const unsigned long long mb = __ballot(pred);
    if (pred){
      const int pos = cnt + __popcll(mb & ((1ull<<lane)-1ull));
      if (pos < 128) ll_s[wv][pos] = (unsigned short)j;
    }
    cnt += (int)__popcll(mb);
  }
  if (lane == 0) cnts[bc*N_+gi] = cnt;
  __syncthreads();
  lp[lane]    = ll_s[wv][lane];
  lp[lane+64] = ll_s[wv][lane+64];
  if (cnt <= 128 && lane < 32){
    int myc = 0;
    for (int kk=0; kk<cnt; ++kk){
      const int j = ll_s[wv][kk];
      const int sl = ((j>>7)<<3) | (j&7);
      myc += (sl == lane);
    }
    scn_s[wv][lane] = myc;
  }
  __syncthreads();
  if (cnt <= 128 && lane < 32){
    const int s = lane;
    int off = 0;
    for (int u=0; u<s; ++u) off += scn_s[wv][u];
    soff[rb*33 + s] = (unsigned short)off;
    if (s == 0) soff[rb*33 + 32] = (unsigned short)cnt;
    int pos = off;
    unsigned short* sk = slotkk + rb*128;
    for (int kk=0; kk<cnt; ++kk){
      const int j = ll_s[wv][kk];
      const int sl = ((j>>7)<<3) | (j&7);
      if (sl == s){ sk[pos] = (unsigned short)kk; ++pos; }
    }
  }
}

// ---- sgemm emu, 128x64 tile, BK=16, DOUBLE-BUFFERED LDS (1 barrier/K-step).
// Per-element FP: identical sequential-k 512-FMA chain; only barrier schedule changes. ----
__global__ __launch_bounds__(256) void gemm_t(const float* __restrict__ A, const float* __restrict__ W,
                                              float* __restrict__ C){
  __shared__ float As2[2][16][132];  // [buf][k][m], m=128
  __shared__ float Ws[2][16][68];    // [buf][k][c]
  const int t  = threadIdx.x;
  const int nb = gridDim.x*gridDim.y;
  const int id = swz8(blockIdx.y*gridDim.x + blockIdx.x, nb);
  const int c0 = (id & 7)*64, m0 = (id >> 3)*128;
  const int mg = t>>4, cg = t&15;   // 8m x 4c per thread
  const int arow = t>>1, akk = (t&1)*8;   // A stage: row, 8 k
  const int wr = t>>4, wcc = (t&15)*4;    // W stage: k row, 4 c
  float4 av0, av1, wv;
  {
    const float* ap = A + (size_t)(m0+arow)*K_ + akk;
    av0 = *reinterpret_cast<const float4*>(ap);
    av1 = *reinterpret_cast<const float4*>(ap+4);
    wv  = *reinterpret_cast<const float4*>(W + (size_t)wr*HF_ + c0 + wcc);
  }
  // prologue: stage K-step 0 into buf 0
  As2[0][akk+0][arow]=av0.x; As2[0][akk+1][arow]=av0.y; As2[0][akk+2][arow]=av0.z; As2[0][akk+3][arow]=av0.w;
  As2[0][akk+4][arow]=av1.x; As2[0][akk+5][arow]=av1.y; As2[0][akk+6][arow]=av1.z; As2[0][akk+7][arow]=av1.w;
  *reinterpret_cast<float4*>(&Ws[0][wr][wcc]) = wv;
  float acc[8][4] = {};
  for (int kt=0; kt<K_; kt+=16){
    const int p = (kt>>4) & 1;
    __syncthreads();   // buf p writes visible; prior iter's reads of buf p^1 complete
    if (kt+16 < K_){   // prefetch next K-step into regs; latency hides under compute
      const float* ap = A + (size_t)(m0+arow)*K_ + kt + 16 + akk;
      av0 = *reinterpret_cast<const float4*>(ap);
      av1 = *reinterpret_cast<const float4*>(ap+4);
      wv  = *reinterpret_cast<const float4*>(W + (size_t)(kt+16+wr)*HF_ + c0 + wcc);
    }
    #pragma unroll
    for (int k=0;k<16;++k){
      const float4 a40 = *reinterpret_cast<const float4*>(&As2[p][k][mg*8]);
      const float4 a41 = *reinterpret_cast<const float4*>(&As2[p][k][mg*8+4]);
      const float4 w4  = *reinterpret_cast<const float4*>(&Ws[p][k][cg*4]);
      const float am[8] = {a40.x,a40.y,a40.z,a40.w,a41.x,a41.y,a41.z,a41.w};
      #pragma unroll
      for (int q=0;q<8;++q){
        acc[q][0]=f_fma(am[q],w4.x,acc[q][0]); acc[q][1]=f_fma(am[q],w4.y,acc[q][1]);
        acc[q][2]=f_fma(am[q],w4.z,acc[q][2]); acc[q][3]=f_fma(am[q],w4.w,acc[q][3]);
      }
    }
    if (kt+16 < K_){   // stage next K-step into buf p^1 (its prior readers done pre-barrier)
      const int pn = p ^ 1;
      As2[pn][akk+0][arow]=av0.x; As2[pn][akk+1][arow]=av0.y; As2[pn][akk+2][arow]=av0.z; As2[pn][akk+3][arow]=av0.w;
      As2[pn][akk+4][arow]=av1.x; As2[pn][akk+5][arow]=av1.y; As2[pn][akk+6][arow]=av1.z; As2[pn][akk+7][arow]=av1.w;
      *reinterpret_cast<float4*>(&Ws[pn][wr][wcc]) = wv;
    }
  }
  #pragma unroll
  for (int q=0;q<8;++q){
    float4 o = make_float4(acc[q][0],acc[q][1],acc[q][2],acc[q][3]);
    *reinterpret_cast<float4*>(&C[(size_t)(m0+mg*8+q)*HF_ + c0 + cg*4]) = o;
  }
}

// ---- el/er: unchanged ----
__global__ __launch_bounds__(256) void eler_emu(const float* __restrict__ g, const float* __restrict__ a,
                                                float* __restrict__ el, float* __restrict__ er){
  const int gid = blockIdx.x*256 + threadIdx.x;   // (row, h)
  const int row = gid >> 3, h = gid & 7;
  const float* gr = g + (size_t)row*HF_ + h*64;
  float pl = 0.f, pr = 0.f;
  for (int f=0; f<64; ++f){
    pl = f_add(pl, f_mul(gr[f], a[f]));
    pr = f_add(pr, f_mul(gr[f], a[64+f]));
  }
  el[(size_t)row*NH_+h] = pl;
  er[(size_t)row*NH_+h] = pr;
}

// ---- attention: VERBATIM round 21 (known-pass; scalar LDS, slot-major den). ----
__global__ __launch_bounds__(256) void att_sp(const float* __restrict__ g, const float* __restrict__ el,
                                              const float* __restrict__ er, const float* __restrict__ adjc,
                                              const unsigned short* __restrict__ lists,
                                              const int* __restrict__ cnts,
                                              const unsigned short* __restrict__ slotkk,
                                              const unsigned short* __restrict__ soff,
                                              float* __restrict__ hout){
  const int bid = swz8(blockIdx.x, gridDim.x);
  const int it = bid & 31, h = (bid>>5)&7, bc = bid>>8;
  const int i0 = it*16;
  __shared__ float er_s[512];
  __shared__ float el_s[16];
  __shared__ unsigned short list_s[16][128];
  __shared__ float pval_s[16][128];
  __shared__ int   cnt_s[16];
  __shared__ float m_s[16], den_s[16];
  __shared__ float rs[16][33];
  __shared__ float dense_s[513];   // overflow-fallback only
  __shared__ float red[256];       // overflow-fallback only
  const int t = threadIdx.x;
  if (t < 16){ el_s[t] = el[((size_t)(bc*N_) + i0 + t)*NH_ + h]; cnt_s[t] = cnts[bc*N_+i0+t]; }
  er_s[t]     = er[((size_t)(bc*N_) + t)*NH_ + h];
  er_s[t+256] = er[((size_t)(bc*N_) + t + 256)*NH_ + h];
  {
    const int r = t>>4, off = (t&15)*8;
    const unsigned short* lp = lists + ((size_t)(bc*N_)+i0+r)*128 + off;
    #pragma unroll
    for (int q=0;q<8;++q) list_s[r][off+q] = lp[q];
  }
  __syncthreads();
  const int ir = t>>4, l = t&15;
  // e in list order + per-lane max
  {
    const int cnt = cnt_s[ir];
    const float eli = el_s[ir];
    float mx = -INFINITY;
    if (cnt <= 128){
      for (int kk=l; kk<cnt; kk+=16){
        const float e = lrelu_np(f_add(eli, er_s[list_s[ir][kk]]));
        pval_s[ir][kk] = e;
        mx = fmaxf(mx, e);
      }
    }
    rs[ir][l] = mx;
  }
  __syncthreads();
  if (t < 16){
    float m = rs[t][0];
    #pragma unroll
    for (int u=1;u<16;++u) m = fmaxf(m, rs[t][u]);
    m_s[t] = m;
  }
  __syncthreads();
  // exp over list
  {
    const int cnt = cnt_s[ir];
    const float mi = m_s[ir];
    if (cnt <= 128)
      for (int kk=l; kk<cnt; kk+=16)
        pval_s[ir][kk] = expf_cr(f_sub(pval_s[ir][kk], mi));
  }
  __syncthreads();
  // den: numpy pairwise via slot-sums, DIRECT via slot-major index (lane owns slots l, l+16)
  {
    const int cnt = cnt_s[ir];
    if (cnt <= 128){
      const size_t rb = (size_t)(bc*N_) + i0 + ir;
      const unsigned short* sk = slotkk + rb*128;
      const unsigned short* so = soff + rb*33;
      #pragma unroll
      for (int ss=0; ss<2; ++ss){
        const int s = l + ss*16;
        const int o0 = so[s], o1 = so[s+1];
        float r = 0.f;
        for (int o=o0; o<o1; ++o)
          r = f_add(r, pval_s[ir][sk[o]]);
        rs[ir][s] = r;
      }
    }
  }
  __syncthreads();
  if (t < 16 && cnt_s[t] <= 128){
    float pw[4];
    #pragma unroll
    for (int gq=0;gq<4;++gq){
      const float* rr = &rs[t][gq*8];
      pw[gq] = f_add(f_add(f_add(rr[0],rr[1]),f_add(rr[2],rr[3])),
                     f_add(f_add(rr[4],rr[5]),f_add(rr[6],rr[7])));
    }
    den_s[t] = f_add(f_add(pw[0],pw[1]), f_add(pw[2],pw[3]));
  }
  __syncthreads();
  // div over list
  {
    const int cnt = cnt_s[ir];
    const float di = den_s[ir];
    if (cnt <= 128)
      for (int kk=l; kk<cnt; kk+=16)
        pval_s[ir][kk] = f_div(pval_s[ir][kk], di);
  }
  __syncthreads();
  // aggregation: sparse j-ascending chain per (row, f) — SCALAR
  {
    const int f = t & 63, iw = t >> 6;
    const float* gcol = g + (size_t)(bc*N_)*HF_ + h*64 + f;
    const size_t ob = (size_t)(bc*N_) + i0;
    #pragma unroll
    for (int q=0;q<4;++q){
      const int i = iw + q*4;
      const int cnt = cnt_s[i];
      if (cnt > 128) continue;
      float a = 0.f;
      for (int kk=0; kk<cnt; ++kk){
        const int j = list_s[i][kk];
        a = f_add(a, f_mul(pval_s[i][kk], gcol[(size_t)j*HF_]));
      }
      hout[(ob+i)*HF_ + h*64 + f] = lrelu_np(a);
    }
  }
  // dense fallback for overflow rows (cnt>128; kept for unconditional correctness)
  for (int i=0;i<16;++i){
    if (cnt_s[i] <= 128) continue;
    __syncthreads();
    const int gi = i0 + i;
    const float eli = el_s[i];
    for (int s=0;s<2;++s){
      const int j = t + s*256;
      const float av = adjc[((size_t)(bc*N_)+gi)*N_ + j];
      const bool mask = (av != 0.f) || (gi == j);
      dense_s[j] = mask ? lrelu_np(f_add(eli, er_s[j])) : -1000.0f;
    }
    __syncthreads();
    red[t] = fmaxf(dense_s[t], dense_s[t+256]);
    __syncthreads();
    for (int s2=128; s2>=1; s2>>=1){ if (t<s2) red[t]=fmaxf(red[t],red[t+s2]); __syncthreads(); }
    const float mi = red[0];
    __syncthreads();
    for (int s=0;s<2;++s){
      const int j = t + s*256;
      const float v = dense_s[j];
      dense_s[j] = (v == -1000.0f) ? 0.0f : expf_cr(f_sub(v, mi));
    }
    __syncthreads();
    if (t < 32){
      const int gq = t>>3, ll = t&7;
      float r = dense_s[gq*128 + ll];
      for (int m2=1;m2<16;++m2) r = f_add(r, dense_s[gq*128 + m2*8 + ll]);
      rs[0][t] = r;
    }
    __syncthreads();
    if (t == 0){
      float pw[4];
      for (int gq=0;gq<4;++gq){
        const float* rr = &rs[0][gq*8];
        pw[gq] = f_add(f_add(f_add(rr[0],rr[1]),f_add(rr[2],rr[3])),
                       f_add(f_add(rr[4],rr[5]),f_add(rr[6],rr[7])));
      }
      den_s[0] = f_add(f_add(pw[0],pw[1]), f_add(pw[2],pw[3]));
    }
    __syncthreads();
    {
      const float di = den_s[0];
      for (int s=0;s<2;++s){ const int j=t+s*256; dense_s[j] = f_div(dense_s[j], di); }
    }
    __syncthreads();
    if (t < 64){
      const float* gcol = g + (size_t)(bc*N_)*HF_ + h*64 + t;
      float a = 0.f;
      for (int j=0;j<512;++j) a = f_add(a, f_mul(dense_s[j], gcol[(size_t)j*HF_]));
      hout[((size_t)(bc*N_)+gi)*HF_ + h*64 + t] = lrelu_np(a);
    }
  }
}

// ---- scores: unchanged ----
__global__ __launch_bounds__(256) void scores_emu(const float* __restrict__ h2, const float* __restrict__ Wp,
                                                  const float* __restrict__ bp, float* __restrict__ sc){
  const int r = blockIdx.x*256 + threadIdx.x;   // (bc, n)
  const float* hr = h2 + (size_t)r*HF_;
  float q0=0,q1=0,q2=0,q3=0,q4=0,q5=0,q6=0,q7=0;
  for (int k=0;k<512;k+=8){
    q0=f_fma(hr[k+0],Wp[k+0],q0); q1=f_fma(hr[k+1],Wp[k+1],q1);
    q2=f_fma(hr[k+2],Wp[k+2],q2); q3=f_fma(hr[k+3],Wp[k+3],q3);
    q4=f_fma(hr[k+4],Wp[k+4],q4); q5=f_fma(hr[k+5],Wp[k+5],q5);
    q6=f_fma(hr[k+6],Wp[k+6],q6); q7=f_fma(hr[k+7],Wp[k+7],q7);
  }
  const float d = f_add(f_add(f_add(q0,q4),f_add(q1,q5)), f_add(f_add(q2,q6),f_add(q3,q7)));
  sc[r] = f_add(d, bp[0]);
}

// ---- stable top-256 rank counting (unchanged) ----
__global__ __launch_bounds__(512) void topk_f(const float* __restrict__ sc, int* __restrict__ idx){
  __shared__ float sl[512];
  const int b = blockIdx.x, t = threadIdx.x;
  if (t < 256) idx[b*256+t] = t;
  sl[t] = sc[(size_t)b*N_+t];
  __syncthreads();
  const float mine = sl[t];
  int cnt = 0;
  for (int j=0;j<N_;++j){
    const float v = sl[j];
    cnt += (v > mine) || (v == mine && j < t);
  }
  if (cnt < 256) idx[b*256+cnt] = t;
}

__global__ __launch_bounds__(128) void gather_f(const float* __restrict__ h2, const int* __restrict__ idx,
                                                float* __restrict__ outc){
  const int r = blockIdx.x;
  const int bc = r>>8, kk = r&255;
  const int n = idx[bc*256+kk] & (N_-1);
  const int t = threadIdx.x;
  const float4 v = *reinterpret_cast<const float4*>(&h2[(size_t)(bc*N_+n)*HF_ + t*4]);
  *reinterpret_cast<float4*>(&outc[(size_t)(bc*256+kk)*HF_ + t*4]) = v;
}

extern "C" void kernel_launch(void* const* d_in, const int* in_sizes, int n_in,
                              void* d_out, int out_size, void* d_ws, size_t ws_size,
                              hipStream_t stream){
  const float* x   = (const float*)d_in[0];
  const float* adj = (const float*)d_in[1];
  const float* W1  = (const float*)d_in[2];
  const float* a1  = (const float*)d_in[3];
  const float* W2  = (const float*)d_in[4];
  const float* a2  = (const float*)d_in[5];
  const float* Wp  = (const float*)d_in[6];
  const float* bp  = (const float*)d_in[7];

  // per-batch: g/h1/h2 1MiB + el/er 16KiB + sc 2KiB + idx 1KiB + lists 128KiB + cnts 2KiB
  //            + slotkk 128KiB + soff 33.75KiB(512*66B)  => 3,480,320 (rounded up)
  const size_t per = 3480320;
  int C = B_;
  while (C > 1 && per*(size_t)C > ws_size) C >>= 1;

  char* w    = (char*)d_ws;
  float* g   = (float*)w;
  float* h1  = (float*)(w + (size_t)C*1048576);
  float* h2  = (float*)(w + (size_t)2*C*1048576);
  float* el  = (float*)(w + (size_t)3*C*1048576);
  float* er  = el + (size_t)C*4096;
  float* sc  = er + (size_t)C*4096;
  int*  idx  = (int*)(sc + (size_t)C*512);
  unsigned short* lists  = (unsigned short*)((char*)idx + (size_t)C*1024);
  int*  cnts             = (int*)((char*)lists + (size_t)C*131072);
  unsigned short* slotkk = (unsigned short*)((char*)cnts + (size_t)C*2048);
  unsigned short* soff   = (unsigned short*)((char*)slotkk + (size_t)C*131072);

  for (int b0 = 0; b0 < B_; b0 += C){
    const float* xc   = x   + (size_t)b0*N_*K_;
    const float* adjc = adj + (size_t)b0*N_*N_;
    float* outc = (float*)d_out + (size_t)b0*256*HF_;
    const int M = C*N_;
    dim3 gg(HF_/64, M/128);
    build_lists<<<C*128, 256, 0, stream>>>(adjc, lists, cnts, slotkk, soff);
    // layer 1
    gemm_t<<<gg, 256, 0, stream>>>(xc, W1, g);
    eler_emu<<<(M*NH_)/256, 256, 0, stream>>>(g, a1, el, er);
    att_sp<<<C*NH_*32, 256, 0, stream>>>(g, el, er, adjc, lists, cnts, slotkk, soff, h1);
    // layer 2
    gemm_t<<<gg, 256, 0, stream>>>(h1, W2, g);
    eler_emu<<<(M*NH_)/256, 256, 0, stream>>>(g, a2, el, er);
    att_sp<<<C*NH_*32, 256, 0, stream>>>(g, el, er, adjc, lists, cnts, slotkk, soff, h2);
    // pool
    scores_emu<<<M/256, 256, 0, stream>>>(h2, Wp, bp, sc);
    topk_f<<<C, 512, 0, stream>>>(sc, idx);
    gather_f<<<C*256, 128, 0, stream>>>(h2, idx, outc);
  }
}